// Round 9
// baseline (691.638 us; speedup 1.0000x reference)
//
#include <hip/hip_runtime.h>

#define T_TOK 32768
#define HDIM  512
#define IDIM  1024
#define NEXP  8
#define CHUNK 16384
#define NCHUNK 5

typedef float    f32x4 __attribute__((ext_vector_type(4)));
typedef _Float16 f16x8 __attribute__((ext_vector_type(8)));
typedef _Float16 f16x4 __attribute__((ext_vector_type(4)));

// global_load_lds, 16B per lane, LDS dest = wave-uniform base + lane*16
#define GL2LDS(gp, lp)                                                        \
    __builtin_amdgcn_global_load_lds(                                         \
        (const __attribute__((address_space(1))) void*)(gp),                  \
        (__attribute__((address_space(3))) void*)(lp), 16, 0, 0)

// ---------------------------------------------------------------------------
// Router (unchanged, proven): logits, top-2, softmax, bucket append.
// ---------------------------------------------------------------------------
__global__ __launch_bounds__(256) void router_kernel(
    const float* __restrict__ x, const float* __restrict__ rw,
    const float* __restrict__ rb, int* __restrict__ cnt,
    int* __restrict__ btok, float* __restrict__ bw)
{
    __shared__ float Wl[HDIM * NEXP];
    __shared__ float xc[64 * 133];
    __shared__ float part[4 * 64 * 8];
    __shared__ int   bcnt[NEXP];
    __shared__ int   sbase[NEXP];

    const int tid = threadIdx.x;
    const int t0  = blockIdx.x * 64;

    if (tid < NEXP) bcnt[tid] = 0;

    for (int j = tid; j < HDIM * NEXP / 4; j += 256)
        ((float4*)Wl)[j] = ((const float4*)rw)[j];

    const int tl = tid & 63;
    const int q  = tid >> 6;

    float acc[8];
#pragma unroll
    for (int e = 0; e < 8; ++e) acc[e] = 0.f;

    for (int hc = 0; hc < 4; ++hc) {
        __syncthreads();
        for (int j = tid; j < 64 * 128 / 4; j += 256) {
            int row = j >> 5;
            int col = (j & 31) * 4;
            float4 v = *(const float4*)(x + (size_t)(t0 + row) * HDIM + hc * 128 + col);
            float* d = &xc[row * 133 + col];
            d[0] = v.x; d[1] = v.y; d[2] = v.z; d[3] = v.w;
        }
        __syncthreads();
#pragma unroll
        for (int hh = 0; hh < 32; ++hh) {
            int h = q * 32 + hh;
            float xv = xc[tl * 133 + h];
            const float* wrow = &Wl[(hc * 128 + h) * 8];
#pragma unroll
            for (int e = 0; e < 8; ++e) acc[e] += xv * wrow[e];
        }
    }
#pragma unroll
    for (int e = 0; e < 8; ++e) part[(q * 64 + tl) * 8 + e] = acc[e];
    __syncthreads();

    int e0 = 0, e1 = 0, l0 = 0, l1 = 0;
    float w0 = 0.f, w1 = 0.f;
    if (tid < 64) {
        float lg[8];
#pragma unroll
        for (int e = 0; e < 8; ++e)
            lg[e] = part[(0 * 64 + tid) * 8 + e] + part[(1 * 64 + tid) * 8 + e] +
                    part[(2 * 64 + tid) * 8 + e] + part[(3 * 64 + tid) * 8 + e] + rb[e];
#pragma unroll
        for (int e = 1; e < 8; ++e) if (lg[e] > lg[e0]) e0 = e;
        e1 = (e0 == 0) ? 1 : 0;
#pragma unroll
        for (int e = 0; e < 8; ++e) if (e != e0 && lg[e] > lg[e1]) e1 = e;
        float z = __expf(lg[e1] - lg[e0]);
        w0 = 1.f / (1.f + z);
        w1 = z * w0;
        l0 = atomicAdd(&bcnt[e0], 1);
        l1 = atomicAdd(&bcnt[e1], 1);
    }
    __syncthreads();
    if (tid < NEXP) sbase[tid] = atomicAdd(&cnt[tid], bcnt[tid]);
    __syncthreads();
    if (tid < 64) {
        int t  = t0 + tid;
        int s0 = sbase[e0] + l0;
        btok[e0 * T_TOK + s0] = t;  bw[e0 * T_TOK + s0] = w0;
        int s1 = sbase[e1] + l1;
        btok[e1 * T_TOK + s1] = t;  bw[e1 * T_TOK + s1] = w1;
    }
}

// ---------------------------------------------------------------------------
// Transpose + fp32->fp16 convert (unchanged): [E][R][C] f32 -> [E][C][R] f16
// ---------------------------------------------------------------------------
template <int R, int C>
__global__ __launch_bounds__(256) void transpose_cvt(
    const float* __restrict__ src, _Float16* __restrict__ dst)
{
    __shared__ float tile[32][33];
    const int e  = blockIdx.z;
    const int rb = blockIdx.y * 32, cb = blockIdx.x * 32;
    const int t  = threadIdx.x;
    {
        const int lr = t >> 3, lc = (t & 7) * 4;
        float4 v = *(const float4*)(src + ((size_t)e * R + rb + lr) * C + cb + lc);
        tile[lr][lc + 0] = v.x; tile[lr][lc + 1] = v.y;
        tile[lr][lc + 2] = v.z; tile[lr][lc + 3] = v.w;
    }
    __syncthreads();
    {
        const int c = t >> 3, r4 = (t & 7) * 4;
        f16x4 h;
        h[0] = (_Float16)tile[r4 + 0][c];
        h[1] = (_Float16)tile[r4 + 1][c];
        h[2] = (_Float16)tile[r4 + 2][c];
        h[3] = (_Float16)tile[r4 + 3][c];
        *(f16x4*)(dst + ((size_t)e * C + cb + c) * R + rb + r4) = h;
    }
}

// ---------------------------------------------------------------------------
// Prefix: eb[e] = 128-aligned exclusive prefix sum of cnt; eb[8] = total.
// 128-alignment guarantees no GEMM block spans two experts.
// ---------------------------------------------------------------------------
__global__ void prefix_kernel(const int* __restrict__ cnt, int* __restrict__ eb)
{
    if (threadIdx.x == 0 && blockIdx.x == 0) {
        int a = 0;
#pragma unroll
        for (int e = 0; e < 8; ++e) { eb[e] = a; a += (cnt[e] + 127) & ~127; }
        eb[8] = a;
    }
}

// ---------------------------------------------------------------------------
// Repack into the padded global slot space; pads get (valid token 0, w=0).
// ---------------------------------------------------------------------------
__global__ __launch_bounds__(256) void repack_kernel(
    const int* __restrict__ cnt, const int* __restrict__ eb,
    const int* __restrict__ btok, const float* __restrict__ bw,
    int* __restrict__ btok_p, float* __restrict__ bw_p)
{
    const int e = blockIdx.y;
    const int i = blockIdx.x * 256 + threadIdx.x;
    const int span = eb[e + 1] - eb[e];
    if (i >= span) return;
    const int c = cnt[e];
    const int p = eb[e] + i;
    if (i < c) { btok_p[p] = btok[e * T_TOK + i]; bw_p[p] = bw[e * T_TOK + i]; }
    else       { btok_p[p] = (c > 0) ? btok[e * T_TOK] : 0; bw_p[p] = 0.f; }
}

// ---------------------------------------------------------------------------
// K1: act[slot][I] = (up+1)*quick_gelu(gate), gate/up = x[tok] @ Wgu + b.
// m97 geometry: 256 thr / 4 waves (2x2), tile 128 slots x 64 I-cols, BK=32
// dbuf, LDS 32.5 KB -> 3-4 blocks/CU. A reg-staged (f32 gather + cvt);
// B (gate+up) via global_load_lds with chunk-XOR source pre-swizzle
// (slot c holds data chunk c^(row&3); reads use byte ^ ((row&3)<<4)).
// One __syncthreads per K-step (T3-minimum); cross-block TLP hides the drain.
// ---------------------------------------------------------------------------
__global__ __launch_bounds__(256) void k1_gateup(
    const float* __restrict__ x,
    const _Float16* __restrict__ wgu_t,   // [E][2I][H]
    const float* __restrict__ bgu,        // [E][2I]
    const int* __restrict__ eb,
    const int* __restrict__ btok_p,
    _Float16* __restrict__ act,           // [CHUNK][IDIM]
    int chunk)
{
    const int gs0 = chunk * CHUNK + blockIdx.x * 128;
    if (gs0 >= eb[8]) return;
    int e = 0;
#pragma unroll
    for (int k = 1; k < 8; ++k) if (eb[k] <= gs0) e = k;
    const int n0 = blockIdx.y * 64;

    __shared__ __align__(16) _Float16 Ab[2][128 * 32];   // 8 KB each
    __shared__ __align__(16) _Float16 Bg[2][64 * 32];    // 4 KB each
    __shared__ __align__(16) _Float16 Bu[2][64 * 32];    // 4 KB each
    __shared__ int s_tok[128];

    const int tid  = threadIdx.x;
    const int lane = tid & 63;
    const int w    = tid >> 6;            // 0..3
    const int wm   = w >> 1, wn = w & 1;  // 2x2 wave grid
    const int bn   = lane & 15;
    const int bq   = lane >> 4;
    const int bk2  = bq * 16;             // k-fragment byte offset (16B chunk)

    if (tid < 128) s_tok[tid] = btok_p[gs0 + tid];
    __syncthreads();

    // A reg-stage: thread -> row ar, 16 f32 (half a 32-k window)
    const int ar = tid >> 1;
    const int ah = tid & 1;
    const float* axp = x + (size_t)s_tok[ar] * HDIM + ah * 16;
    const int ab0 = ar * 64 + ((ah * 32)      ^ ((ar & 3) << 4));
    const int ab1 = ar * 64 + ((ah * 32 + 16) ^ ((ar & 3) << 4));

    // B DMA source decode: lane -> (row-local rl, chunk ch), source chunk ch^(rl&3)
    const int rl = lane >> 2, ch = lane & 3;
    const _Float16* bsg = wgu_t + ((size_t)e * 2 * IDIM + n0 + w * 16 + rl) * HDIM
                          + (ch ^ (rl & 3)) * 8;
    const _Float16* bsu = bsg + (size_t)IDIM * HDIM;
    _Float16* dg0 = &Bg[0][w * 512] + lane * 8;
    _Float16* du0 = &Bu[0][w * 512] + lane * 8;
    _Float16* dg1 = &Bg[1][w * 512] + lane * 8;
    _Float16* du1 = &Bu[1][w * 512] + lane * 8;

    f32x4 aG[4][2], aU[4][2];
#pragma unroll
    for (int mt = 0; mt < 4; ++mt)
#pragma unroll
        for (int nt = 0; nt < 2; ++nt)
#pragma unroll
            for (int r = 0; r < 4; ++r) { aG[mt][nt][r] = 0.f; aU[mt][nt][r] = 0.f; }

    // prologue: stage step 0 into buf0
    {
        const float4* p = (const float4*)axp;
        float4 v0 = p[0], v1 = p[1], v2 = p[2], v3 = p[3];
        f16x8 h0, h1;
        h0[0]=(_Float16)v0.x; h0[1]=(_Float16)v0.y; h0[2]=(_Float16)v0.z; h0[3]=(_Float16)v0.w;
        h0[4]=(_Float16)v1.x; h0[5]=(_Float16)v1.y; h0[6]=(_Float16)v1.z; h0[7]=(_Float16)v1.w;
        h1[0]=(_Float16)v2.x; h1[1]=(_Float16)v2.y; h1[2]=(_Float16)v2.z; h1[3]=(_Float16)v2.w;
        h1[4]=(_Float16)v3.x; h1[5]=(_Float16)v3.y; h1[6]=(_Float16)v3.z; h1[7]=(_Float16)v3.w;
        *(f16x8*)((char*)Ab[0] + ab0) = h0;
        *(f16x8*)((char*)Ab[0] + ab1) = h1;
        GL2LDS(bsg, dg0);
        GL2LDS(bsu, du0);
    }
    __syncthreads();

    for (int ks = 0; ks < 16; ++ks) {
        const int cur = ks & 1;
        float4 v0, v1, v2, v3;
        if (ks < 15) {
            const float4* p = (const float4*)(axp + (ks + 1) * 32);
            v0 = p[0]; v1 = p[1]; v2 = p[2]; v3 = p[3];
            GL2LDS(bsg + (ks + 1) * 32, cur ? dg0 : dg1);
            GL2LDS(bsu + (ks + 1) * 32, cur ? du0 : du1);
        }

        const char* ab = (const char*)Ab[cur];
        const char* gb = (const char*)Bg[cur];
        const char* ub = (const char*)Bu[cur];
        f16x8 bgf[2], buf_[2];
#pragma unroll
        for (int nt = 0; nt < 2; ++nt) {
            const int j = wn * 32 + nt * 16 + bn;
            const int byte = j * 64 + (bk2 ^ ((j & 3) << 4));
            bgf[nt]  = *(const f16x8*)(gb + byte);
            buf_[nt] = *(const f16x8*)(ub + byte);
        }
#pragma unroll
        for (int mt = 0; mt < 4; ++mt) {
            const int m = wm * 64 + mt * 16 + bn;
            const int byte = m * 64 + (bk2 ^ ((m & 3) << 4));
            f16x8 af = *(const f16x8*)(ab + byte);
            aG[mt][0] = __builtin_amdgcn_mfma_f32_16x16x32_f16(af, bgf[0],  aG[mt][0], 0, 0, 0);
            aG[mt][1] = __builtin_amdgcn_mfma_f32_16x16x32_f16(af, bgf[1],  aG[mt][1], 0, 0, 0);
            aU[mt][0] = __builtin_amdgcn_mfma_f32_16x16x32_f16(af, buf_[0], aU[mt][0], 0, 0, 0);
            aU[mt][1] = __builtin_amdgcn_mfma_f32_16x16x32_f16(af, buf_[1], aU[mt][1], 0, 0, 0);
        }

        if (ks < 15) {
            f16x8 h0, h1;
            h0[0]=(_Float16)v0.x; h0[1]=(_Float16)v0.y; h0[2]=(_Float16)v0.z; h0[3]=(_Float16)v0.w;
            h0[4]=(_Float16)v1.x; h0[5]=(_Float16)v1.y; h0[6]=(_Float16)v1.z; h0[7]=(_Float16)v1.w;
            h1[0]=(_Float16)v2.x; h1[1]=(_Float16)v2.y; h1[2]=(_Float16)v2.z; h1[3]=(_Float16)v2.w;
            h1[4]=(_Float16)v3.x; h1[5]=(_Float16)v3.y; h1[6]=(_Float16)v3.z; h1[7]=(_Float16)v3.w;
            char* an = (char*)Ab[cur ^ 1];
            *(f16x8*)(an + ab0) = h0;
            *(f16x8*)(an + ab1) = h1;
        }
        __syncthreads();
    }

    // epilogue: bias + quick_gelu -> act (fp16)
    float gB[2], uB[2];
    int jcol[2];
#pragma unroll
    for (int nt = 0; nt < 2; ++nt) {
        jcol[nt] = n0 + wn * 32 + nt * 16 + bn;
        gB[nt] = bgu[e * 2 * IDIM + jcol[nt]];
        uB[nt] = bgu[e * 2 * IDIM + IDIM + jcol[nt]];
    }
#pragma unroll
    for (int mt = 0; mt < 4; ++mt) {
#pragma unroll
        for (int r = 0; r < 4; ++r) {
            const int rr = wm * 64 + mt * 16 + bq * 4 + r;
            _Float16* arow = act + (size_t)(blockIdx.x * 128 + rr) * IDIM;
#pragma unroll
            for (int nt = 0; nt < 2; ++nt) {
                float g = aG[mt][nt][r] + gB[nt];
                float u = aU[mt][nt][r] + uB[nt];
                float a = (u + 1.f) * g / (1.f + __expf(-1.702f * g));
                arow[jcol[nt]] = (_Float16)a;
            }
        }
    }
}

// ---------------------------------------------------------------------------
// K2: out[tok] += w * (act @ Wd + bd). Tile 128 slots x 128 H, K=1024, BK=32
// dbuf, LDS 32 KB -> 4 blocks/CU. A and B both via global_load_lds (chunk-XOR
// pre-swizzled source). Epilogue: weighted atomic scatter (w=0 kills pads).
// ---------------------------------------------------------------------------
__global__ __launch_bounds__(256) void k2_down(
    const _Float16* __restrict__ act,     // [CHUNK][IDIM]
    const _Float16* __restrict__ wd_t,    // [E][H][I]
    const float* __restrict__ bd,         // [E][H]
    const int* __restrict__ eb,
    const int* __restrict__ btok_p,
    const float* __restrict__ bw_p,
    float* __restrict__ out, int chunk)
{
    const int gs0 = chunk * CHUNK + blockIdx.x * 128;
    if (gs0 >= eb[8]) return;
    int e = 0;
#pragma unroll
    for (int k = 1; k < 8; ++k) if (eb[k] <= gs0) e = k;
    const int h0 = blockIdx.y * 128;

    __shared__ __align__(16) _Float16 Ab[2][128 * 32];   // 8 KB each
    __shared__ __align__(16) _Float16 Bb[2][128 * 32];   // 8 KB each
    __shared__ int   s_tok[128];
    __shared__ float s_w[128];

    const int tid  = threadIdx.x;
    const int lane = tid & 63;
    const int w    = tid >> 6;
    const int wm   = w >> 1, wn = w & 1;
    const int bn   = lane & 15;
    const int bq   = lane >> 4;
    const int bk2  = bq * 16;

    if (tid < 128) { s_tok[tid] = btok_p[gs0 + tid]; s_w[tid] = bw_p[gs0 + tid]; }

    // DMA source decode (2 instrs per wave per operand, 16 rows each)
    const int rl = lane >> 2, ch = lane & 3;
    const int swz8 = (ch ^ (rl & 3)) * 8;
    const _Float16* as0 = act + (size_t)(blockIdx.x * 128 + w * 32 + rl) * IDIM + swz8;
    const _Float16* as1 = as0 + (size_t)16 * IDIM;
    const _Float16* bs0 = wd_t + ((size_t)e * HDIM + h0 + w * 32 + rl) * IDIM + swz8;
    const _Float16* bs1 = bs0 + (size_t)16 * IDIM;

    f32x4 acc[4][4];
#pragma unroll
    for (int mt = 0; mt < 4; ++mt)
#pragma unroll
        for (int nt = 0; nt < 4; ++nt)
#pragma unroll
            for (int r = 0; r < 4; ++r) acc[mt][nt][r] = 0.f;

    // prologue: stage step 0
    GL2LDS(as0, &Ab[0][w * 1024] + lane * 8);
    GL2LDS(as1, &Ab[0][w * 1024 + 512] + lane * 8);
    GL2LDS(bs0, &Bb[0][w * 1024] + lane * 8);
    GL2LDS(bs1, &Bb[0][w * 1024 + 512] + lane * 8);
    __syncthreads();

    for (int ks = 0; ks < 32; ++ks) {
        const int cur = ks & 1;
        if (ks < 31) {
            const int ko = (ks + 1) * 32;
            _Float16* a0 = &Ab[cur ^ 1][w * 1024] + lane * 8;
            _Float16* b0 = &Bb[cur ^ 1][w * 1024] + lane * 8;
            GL2LDS(as0 + ko, a0);
            GL2LDS(as1 + ko, a0 + 512);
            GL2LDS(bs0 + ko, b0);
            GL2LDS(bs1 + ko, b0 + 512);
        }

        const char* ab = (const char*)Ab[cur];
        const char* bb = (const char*)Bb[cur];
        f16x8 bf[4];
#pragma unroll
        for (int nt = 0; nt < 4; ++nt) {
            const int n = wn * 64 + nt * 16 + bn;
            bf[nt] = *(const f16x8*)(bb + n * 64 + (bk2 ^ ((n & 3) << 4)));
        }
#pragma unroll
        for (int mt = 0; mt < 4; ++mt) {
            const int m = wm * 64 + mt * 16 + bn;
            f16x8 af = *(const f16x8*)(ab + m * 64 + (bk2 ^ ((m & 3) << 4)));
#pragma unroll
            for (int nt = 0; nt < 4; ++nt)
                acc[mt][nt] = __builtin_amdgcn_mfma_f32_16x16x32_f16(af, bf[nt], acc[mt][nt], 0, 0, 0);
        }
        __syncthreads();
    }

    // epilogue: weighted atomic scatter
    float bdv[4];
    int   col[4];
#pragma unroll
    for (int nt = 0; nt < 4; ++nt) {
        col[nt] = h0 + wn * 64 + nt * 16 + bn;
        bdv[nt] = bd[e * HDIM + col[nt]];
    }
#pragma unroll
    for (int mt = 0; mt < 4; ++mt) {
#pragma unroll
        for (int r = 0; r < 4; ++r) {
            const int rr = wm * 64 + mt * 16 + bq * 4 + r;
            const float wt = s_w[rr];
            if (wt == 0.f) continue;
            float* orow = out + (size_t)s_tok[rr] * HDIM;
#pragma unroll
            for (int nt = 0; nt < 4; ++nt)
                atomicAdd(orow + col[nt], wt * (acc[mt][nt][r] + bdv[nt]));
        }
    }
}

// ---------------------------------------------------------------------------
extern "C" void kernel_launch(void* const* d_in, const int* in_sizes, int n_in,
                              void* d_out, int out_size, void* d_ws, size_t ws_size,
                              hipStream_t stream)
{
    const float* x   = (const float*)d_in[0];
    const float* rw  = (const float*)d_in[1];
    const float* rb  = (const float*)d_in[2];
    const float* wgu = (const float*)d_in[3];
    const float* bgu = (const float*)d_in[4];
    const float* wd  = (const float*)d_in[5];
    const float* bd  = (const float*)d_in[6];
    float* out = (float*)d_out;

    char* ws = (char*)d_ws;
    size_t o = 0;
    int*   cnt    = (int*)(ws + o);   o += 256;
    int*   eb     = (int*)(ws + o);   o += 256;
    int*   btok   = (int*)(ws + o);   o += (size_t)NEXP * T_TOK * 4;        // 1 MB
    float* bwp    = (float*)(ws + o); o += (size_t)NEXP * T_TOK * 4;        // 1 MB
    int*   btok_p = (int*)(ws + o);   o += (size_t)NCHUNK * CHUNK * 4;      // 320 KB
    float* bw_p   = (float*)(ws + o); o += (size_t)NCHUNK * CHUNK * 4;      // 320 KB
    _Float16* wgu_t = (_Float16*)(ws + o); o += (size_t)NEXP * 2 * IDIM * HDIM * 2;  // 16.8 MB
    _Float16* wd_t  = (_Float16*)(ws + o); o += (size_t)NEXP * HDIM * IDIM * 2;      // 8.4 MB
    _Float16* act   = (_Float16*)(ws + o); o += (size_t)CHUNK * IDIM * 2;            // 33.6 MB
    // total ~62 MB of workspace

    hipMemsetAsync(cnt, 0, 256, stream);
    hipMemsetAsync(out, 0, (size_t)out_size * 4, stream);

    transpose_cvt<HDIM, 2 * IDIM><<<dim3(2 * IDIM / 32, HDIM / 32, NEXP), 256, 0, stream>>>(wgu, wgu_t);
    transpose_cvt<IDIM, HDIM><<<dim3(HDIM / 32, IDIM / 32, NEXP), 256, 0, stream>>>(wd, wd_t);
    router_kernel<<<T_TOK / 64, 256, 0, stream>>>(x, rw, rb, cnt, btok, bwp);
    prefix_kernel<<<1, 64, 0, stream>>>(cnt, eb);
    repack_kernel<<<dim3(T_TOK / 256, NEXP), 256, 0, stream>>>(cnt, eb, btok, bwp, btok_p, bw_p);

    for (int c = 0; c < NCHUNK; ++c) {
        k1_gateup<<<dim3(CHUNK / 128, IDIM / 64), 256, 0, stream>>>(
            x, wgu_t, bgu, eb, btok_p, act, c);
        k2_down<<<dim3(CHUNK / 128, HDIM / 128), 256, 0, stream>>>(
            act, wd_t, bd, eb, btok_p, bw_p, out, c);
    }
}